// Round 6
// baseline (368.422 us; speedup 1.0000x reference)
//
#include <hip/hip_runtime.h>

#pragma clang fp contract(off)

// ChamferLoss: BS=4, N=M=8192, D=3
// Outputs (concatenated, float):
//   [0*32768 .. )  min over gts  for each pred   [BS, M]
//   [1*32768 .. )  min over preds for each gt    [BS, N]
//   [2*32768 .. )  argmin over gts  (as float)   [BS, M]
//   [3*32768 .. )  argmin over preds (as float)  [BS, N]
//
// Bit-exact numpy (>=1.22, NPYV einsum) fp32 emulation, NO FMA anywhere
// (pragma contract(off) — ROCm's __f*_rn do NOT block contraction):
//   rr = ((x*x + y*y) + z*z)         np.sum pairwise base n<8, identity-seeded:
//                                    ASCENDING from 0
//   zz = ((x0*y0 + x1*y1) + x2*y2)   einsum contig_contig_outstride0_two:
//                                    count=3 < vstep -> scalar FORWARD
//                                    remainder loop: ASCENDING from 0
//   P  = ((rr_n + rr_m) - (2*zz))    left-to-right; *2 exact
// P is operand-symmetric => both reduction directions get identical bits.
// History: FMA-fused variants -> absmax 6560 (out2); desc-zz no-FMA ->
// absmax 1472 (out3, ~1 flip). Ascending-zz is the modern-numpy order.

#define BS    4
#define NPTS  8192
#define CHUNK 1024
#define BLOCK 256

__global__ __launch_bounds__(BLOCK)
void chamfer_kernel(const float* __restrict__ preds,
                    const float* __restrict__ gts,
                    float* __restrict__ out)
{
#pragma clang fp contract(off)
    const int dir = blockIdx.z;   // 0: reduce over gts (per pred), 1: reduce over preds (per gt)
    const int b   = blockIdx.y;
    const int t   = threadIdx.x;
    const int q   = blockIdx.x * BLOCK + t;   // query point index

    const float* qbase = (dir == 0 ? preds : gts) + (size_t)b * NPTS * 3;
    const float* rbase = (dir == 0 ? gts : preds) + (size_t)b * NPTS * 3;
    float* outv = out + (size_t)dir       * BS * NPTS + (size_t)b * NPTS;
    float* outi = out + (size_t)(2 + dir) * BS * NPTS + (size_t)b * NPTS;

    // Query point; norm ascending, plain ops
    const float qx = qbase[(size_t)q * 3 + 0];
    const float qy = qbase[(size_t)q * 3 + 1];
    const float qz = qbase[(size_t)q * 3 + 2];
    const float q0 = qx * qx;
    const float q1 = qy * qy;
    const float q2 = qz * qz;
    const float rq = (q0 + q1) + q2;

    // Staged candidates: x, y, z, rr (16 B/point -> 16 KB)
    __shared__ float sh[CHUNK][4];

    float bestv[4];
    int   besti[4];
#pragma unroll
    for (int j = 0; j < 4; ++j) { bestv[j] = 3.0e38f; besti[j] = 0; }

    const int nchunks = NPTS / CHUNK;
    for (int c = 0; c < nchunks; ++c) {
        __syncthreads();
#pragma unroll
        for (int k = 0; k < CHUNK / BLOCK; ++k) {
            const int i = t + k * BLOCK;
            const size_t n = (size_t)c * CHUNK + i;
            const float x = rbase[n * 3 + 0];
            const float y = rbase[n * 3 + 1];
            const float z = rbase[n * 3 + 2];
            sh[i][0] = x;
            sh[i][1] = y;
            sh[i][2] = z;
            const float a0 = x * x;
            const float a1 = y * y;
            const float a2 = z * z;
            sh[i][3] = (a0 + a1) + a2;     // ascending, no FMA
        }
        __syncthreads();

#pragma unroll 4
        for (int i = 0; i < CHUNK; ++i) {
            const float x  = sh[i][0];
            const float y  = sh[i][1];
            const float z  = sh[i][2];
            const float rr = sh[i][3];
            // modern-numpy einsum remainder: ASCENDING ((d0 + d1) + d2), no FMA
            const float p0 = x * qx;
            const float p1 = y * qy;
            const float p2 = z * qz;
            const float zz = (p0 + p1) + p2;
            // P = (rr_n + rr_m) - (2*zz), left-to-right
            const float tsum = rr + rq;
            const float w    = 2.0f * zz;
            const float v    = tsum - w;
            const int j = i & 3;
            if (v < bestv[j]) { bestv[j] = v; besti[j] = c * CHUNK + i; }
        }
    }

    // Merge the 4 accumulators; numpy argmin = first occurrence on ties.
    float bv = bestv[0];
    int   bi = besti[0];
#pragma unroll
    for (int j = 1; j < 4; ++j) {
        if (bestv[j] < bv || (bestv[j] == bv && besti[j] < bi)) {
            bv = bestv[j];
            bi = besti[j];
        }
    }

    outv[q] = bv;
    outi[q] = (float)bi;
}

extern "C" void kernel_launch(void* const* d_in, const int* in_sizes, int n_in,
                              void* d_out, int out_size, void* d_ws, size_t ws_size,
                              hipStream_t stream)
{
    const float* preds = (const float*)d_in[0];  // [BS, M, 3]
    const float* gts   = (const float*)d_in[1];  // [BS, N, 3]
    // d_in[2] = mask, unused (matches reference)
    float* out = (float*)d_out;

    dim3 grid(NPTS / BLOCK, BS, 2);
    dim3 block(BLOCK);
    chamfer_kernel<<<grid, block, 0, stream>>>(preds, gts, out);
}

// Round 7
// 164.164 us; speedup vs baseline: 2.2442x; 2.2442x over previous
//
#include <hip/hip_runtime.h>

#pragma clang fp contract(off)

// ChamferLoss: BS=4, N=M=8192, D=3
// Outputs (concatenated, float):
//   [0*32768 .. )  min over gts  for each pred   [BS, M]
//   [1*32768 .. )  min over preds for each gt    [BS, N]
//   [2*32768 .. )  argmin over gts  (as float)   [BS, M]
//   [3*32768 .. )  argmin over preds (as float)  [BS, N]
//
// Bit-exact numpy fp32 emulation (verified PASS round 6), NO FMA anywhere
// (pragma contract(off) — ROCm's __f*_rn do NOT block contraction):
//   rr = ((x*x + y*y) + z*z)           ascending
//   zz = ((x0*y0 + x1*y1) + x2*y2)     ascending, no FMA
//   P  = ((rr_n + rr_m) - (2*zz))      left-to-right; *2 exact
// P operand-symmetric => both reduction directions identical bits.
//
// Perf structure (round 7): round-6 was 1 wave/SIMD (grid-limited, occupancy
// 11%, VALUBusy 44% = latency-bound). Now:
//   - QT=4 queries/thread: one ds_read_b128 feeds 4 evaluations
//     (LDS-pipe floor 164us -> ~41us, under the ~75us VALU floor)
//   - SPLITS=16 candidate splits: threads x4 -> 4 waves/SIMD to hide latency
//   - waves are split-uniform -> candidate reads stay wave-uniform broadcasts
//   - merge: lex (v,idx) min over splits == numpy first-occurrence argmin
//     (valid because v is bit-identical regardless of which thread computes it)

#define BS     4
#define NPTS   8192
#define CHUNK  1024
#define BLOCK  1024
#define SPLITS 16
#define SLOTS  64                 // query slots per block
#define QT     4                  // queries per thread
#define QBLK   (SLOTS * QT)       // 256 queries per block
#define ROWS   (CHUNK / SPLITS)   // 64 candidate rows per chunk per split

__global__ __launch_bounds__(BLOCK, 4)
void chamfer_kernel(const float* __restrict__ preds,
                    const float* __restrict__ gts,
                    float* __restrict__ out)
{
#pragma clang fp contract(off)
    const int dir  = blockIdx.z;   // 0: per-pred min over gts, 1: per-gt min over preds
    const int b    = blockIdx.y;
    const int t    = threadIdx.x;
    const int slot  = t & 63;      // query slot within block (wave = 64 slots)
    const int split = t >> 6;      // candidate split (wave-uniform)
    const int qb   = blockIdx.x * QBLK;

    const float* qbase = (dir == 0 ? preds : gts) + (size_t)b * NPTS * 3;
    const float* rbase = (dir == 0 ? gts : preds) + (size_t)b * NPTS * 3;
    float* outv = out + (size_t)dir       * BS * NPTS + (size_t)b * NPTS;
    float* outi = out + (size_t)(2 + dir) * BS * NPTS + (size_t)b * NPTS;

    // QT query points per thread; norms ascending, plain ops
    float qx[QT], qy[QT], qz[QT], rq[QT];
#pragma unroll
    for (int j = 0; j < QT; ++j) {
        const int q = qb + j * SLOTS + slot;
        const float x = qbase[(size_t)q * 3 + 0];
        const float y = qbase[(size_t)q * 3 + 1];
        const float z = qbase[(size_t)q * 3 + 2];
        qx[j] = x; qy[j] = y; qz[j] = z;
        const float a0 = x * x;
        const float a1 = y * y;
        const float a2 = z * z;
        rq[j] = (a0 + a1) + a2;
    }

    // Staged candidates: x, y, z, rr (16 B/point -> 16 KB)
    __shared__ float sh[CHUNK][4];
    // Merge scratch
    __shared__ float shv[SPLITS][SLOTS];
    __shared__ int   shi[SPLITS][SLOTS];

    float bestv[QT];
    int   besti[QT];
#pragma unroll
    for (int j = 0; j < QT; ++j) { bestv[j] = 3.0e38f; besti[j] = 0; }

    const int nchunks = NPTS / CHUNK;
    for (int c = 0; c < nchunks; ++c) {
        __syncthreads();
        {   // stage: each of 1024 threads loads one point
            const size_t n = (size_t)c * CHUNK + t;
            const float x = rbase[n * 3 + 0];
            const float y = rbase[n * 3 + 1];
            const float z = rbase[n * 3 + 2];
            sh[t][0] = x;
            sh[t][1] = y;
            sh[t][2] = z;
            const float a0 = x * x;
            const float a1 = y * y;
            const float a2 = z * z;
            sh[t][3] = (a0 + a1) + a2;     // ascending, no FMA
        }
        __syncthreads();

        const int rbase_row = split * ROWS;
#pragma unroll 4
        for (int k = 0; k < ROWS; ++k) {
            const int row = rbase_row + k;
            const float x  = sh[row][0];
            const float y  = sh[row][1];
            const float z  = sh[row][2];
            const float rr = sh[row][3];
            const int idx = c * CHUNK + row;
#pragma unroll
            for (int j = 0; j < QT; ++j) {
                // zz ascending ((d0 + d1) + d2), no FMA
                const float p0 = x * qx[j];
                const float p1 = y * qy[j];
                const float p2 = z * qz[j];
                const float zz = (p0 + p1) + p2;
                // P = (rr_n + rr_m) - (2*zz), left-to-right
                const float tsum = rr + rq[j];
                const float w    = 2.0f * zz;
                const float v    = tsum - w;
                if (v < bestv[j]) { bestv[j] = v; besti[j] = idx; }
            }
        }
    }

    // Merge over splits; lex (v, idx) min == numpy first-occurrence argmin
#pragma unroll
    for (int j = 0; j < QT; ++j) {
        __syncthreads();
        shv[split][slot] = bestv[j];
        shi[split][slot] = besti[j];
        __syncthreads();
        if (t < SLOTS) {
            float bv = shv[0][t];
            int   bi = shi[0][t];
            for (int s = 1; s < SPLITS; ++s) {
                const float v  = shv[s][t];
                const int   i2 = shi[s][t];
                if (v < bv || (v == bv && i2 < bi)) { bv = v; bi = i2; }
            }
            const int q = qb + j * SLOTS + t;
            outv[q] = bv;
            outi[q] = (float)bi;
        }
    }
}

extern "C" void kernel_launch(void* const* d_in, const int* in_sizes, int n_in,
                              void* d_out, int out_size, void* d_ws, size_t ws_size,
                              hipStream_t stream)
{
    const float* preds = (const float*)d_in[0];  // [BS, M, 3]
    const float* gts   = (const float*)d_in[1];  // [BS, N, 3]
    // d_in[2] = mask, unused (matches reference)
    float* out = (float*)d_out;

    dim3 grid(NPTS / QBLK, BS, 2);   // 32 x 4 x 2 = 256 blocks of 1024
    dim3 block(BLOCK);
    chamfer_kernel<<<grid, block, 0, stream>>>(preds, gts, out);
}

// Round 8
// 126.442 us; speedup vs baseline: 2.9138x; 1.2983x over previous
//
#include <hip/hip_runtime.h>

#pragma clang fp contract(off)

// ChamferLoss: BS=4, N=M=8192, D=3
// Outputs (concatenated, float):
//   [0*32768 .. )  min over gts  for each pred   [BS, M]
//   [1*32768 .. )  min over preds for each gt    [BS, N]
//   [2*32768 .. )  argmin over gts  (as float)   [BS, M]
//   [3*32768 .. )  argmin over preds (as float)  [BS, N]
//
// Bit-exact numpy fp32 emulation (verified PASS rounds 6-7), NO FMA anywhere
// (pragma contract(off) — ROCm's __f*_rn do NOT block contraction):
//   rr = ((x*x + y*y) + z*z)           ascending
//   zz = ((x0*y0 + x1*y1) + x2*y2)     ascending, no FMA
//   P  = ((rr_n + rr_m) - (2*zz))      left-to-right; *2 exact
// P operand-symmetric => both reduction directions identical bits.
//
// Round 8 structure: round 7 was VALU-issue-bound (VALUBusy 88%, occ 45%).
//   - packed fp32: QT=4 queries as 2x f32x2 -> v_pk_mul/add_f32 (VOP3P),
//     2 IEEE-rn ops/inst, same rounding => bit-exactness preserved
//   - SLOTS=32 x SPLITS=32, QBLK=128 -> 512 blocks = 2 blocks/CU
//     = 8 waves/SIMD (launch_bounds caps VGPR at 64)
//   - wave spans 2 splits -> ds_read_b128 2-way broadcast (free, m136)

#define BS     4
#define NPTS   8192
#define CHUNK  1024
#define BLOCK  1024
#define SPLITS 32
#define SLOTS  32                 // query slots per block
#define QT     4                  // queries per thread
#define QBLK   (SLOTS * QT)       // 128 queries per block
#define ROWS   (CHUNK / SPLITS)   // 32 candidate rows per chunk per split

typedef float f32x2 __attribute__((ext_vector_type(2)));

__global__ __launch_bounds__(BLOCK, 8)
void chamfer_kernel(const float* __restrict__ preds,
                    const float* __restrict__ gts,
                    float* __restrict__ out)
{
#pragma clang fp contract(off)
    const int dir   = blockIdx.z;  // 0: per-pred min over gts, 1: per-gt min over preds
    const int b     = blockIdx.y;
    const int t     = threadIdx.x;
    const int slot  = t & (SLOTS - 1);   // query slot within block
    const int split = t >> 5;            // candidate split
    const int qb    = blockIdx.x * QBLK;

    const float* qbase = (dir == 0 ? preds : gts) + (size_t)b * NPTS * 3;
    const float* rbase = (dir == 0 ? gts : preds) + (size_t)b * NPTS * 3;
    float* outv = out + (size_t)dir       * BS * NPTS + (size_t)b * NPTS;
    float* outi = out + (size_t)(2 + dir) * BS * NPTS + (size_t)b * NPTS;

    // QT=4 query points as 2 packed groups (g: j = 2g+h)
    f32x2 qxv[2], qyv[2], qzv[2], rqv[2];
#pragma unroll
    for (int g = 0; g < 2; ++g) {
#pragma unroll
        for (int h = 0; h < 2; ++h) {
            const int j = g * 2 + h;
            const int q = qb + j * SLOTS + slot;
            const float x = qbase[(size_t)q * 3 + 0];
            const float y = qbase[(size_t)q * 3 + 1];
            const float z = qbase[(size_t)q * 3 + 2];
            qxv[g][h] = x; qyv[g][h] = y; qzv[g][h] = z;
            const float a0 = x * x;
            const float a1 = y * y;
            const float a2 = z * z;
            rqv[g][h] = (a0 + a1) + a2;     // ascending, no FMA
        }
    }

    // Staged candidates: x, y, z, rr (16 B/point -> 16 KB)
    __shared__ float sh[CHUNK][4];
    // Merge scratch (8 KB)
    __shared__ float shv[SPLITS][SLOTS];
    __shared__ int   shi[SPLITS][SLOTS];

    float bestv[QT];
    int   besti[QT];
#pragma unroll
    for (int j = 0; j < QT; ++j) { bestv[j] = 3.0e38f; besti[j] = 0; }

    const int nchunks = NPTS / CHUNK;
    for (int c = 0; c < nchunks; ++c) {
        __syncthreads();
        {   // stage: each of 1024 threads loads one point
            const size_t n = (size_t)c * CHUNK + t;
            const float x = rbase[n * 3 + 0];
            const float y = rbase[n * 3 + 1];
            const float z = rbase[n * 3 + 2];
            sh[t][0] = x;
            sh[t][1] = y;
            sh[t][2] = z;
            const float a0 = x * x;
            const float a1 = y * y;
            const float a2 = z * z;
            sh[t][3] = (a0 + a1) + a2;     // ascending, no FMA
        }
        __syncthreads();

        const int row0 = split * ROWS;
#pragma unroll 4
        for (int k = 0; k < ROWS; ++k) {
            const int row = row0 + k;
            const float x  = sh[row][0];
            const float y  = sh[row][1];
            const float z  = sh[row][2];
            const float rr = sh[row][3];
            const int idx = c * CHUNK + row;
#pragma unroll
            for (int g = 0; g < 2; ++g) {
                // zz ascending ((d0 + d1) + d2), packed IEEE-rn, no FMA
                const f32x2 p0 = qxv[g] * x;
                const f32x2 p1 = qyv[g] * y;
                const f32x2 p2 = qzv[g] * z;
                const f32x2 zz = (p0 + p1) + p2;
                const f32x2 ts = rqv[g] + rr;    // == rr + rq (commutative)
                const f32x2 w  = zz * 2.0f;
                const f32x2 v  = ts - w;
                if (v[0] < bestv[2 * g + 0]) { bestv[2 * g + 0] = v[0]; besti[2 * g + 0] = idx; }
                if (v[1] < bestv[2 * g + 1]) { bestv[2 * g + 1] = v[1]; besti[2 * g + 1] = idx; }
            }
        }
    }

    // Merge over splits; lex (v, idx) min == numpy first-occurrence argmin
    // (valid: v is bit-identical regardless of which split computes it)
#pragma unroll
    for (int j = 0; j < QT; ++j) {
        __syncthreads();
        shv[split][slot] = bestv[j];
        shi[split][slot] = besti[j];
        __syncthreads();
        if (t < SLOTS) {
            float bv = shv[0][t];
            int   bi = shi[0][t];
            for (int s = 1; s < SPLITS; ++s) {
                const float v2 = shv[s][t];
                const int   i2 = shi[s][t];
                if (v2 < bv || (v2 == bv && i2 < bi)) { bv = v2; bi = i2; }
            }
            const int q = qb + j * SLOTS + t;
            outv[q] = bv;
            outi[q] = (float)bi;
        }
    }
}

extern "C" void kernel_launch(void* const* d_in, const int* in_sizes, int n_in,
                              void* d_out, int out_size, void* d_ws, size_t ws_size,
                              hipStream_t stream)
{
    const float* preds = (const float*)d_in[0];  // [BS, M, 3]
    const float* gts   = (const float*)d_in[1];  // [BS, N, 3]
    // d_in[2] = mask, unused (matches reference)
    float* out = (float*)d_out;

    dim3 grid(NPTS / QBLK, BS, 2);   // 64 x 4 x 2 = 512 blocks of 1024
    dim3 block(BLOCK);
    chamfer_kernel<<<grid, block, 0, stream>>>(preds, gts, out);
}

// Round 9
// 117.886 us; speedup vs baseline: 3.1252x; 1.0726x over previous
//
#include <hip/hip_runtime.h>

#pragma clang fp contract(off)

// ChamferLoss: BS=4, N=M=8192, D=3
// Outputs (concatenated, float):
//   [0*32768 .. )  min over gts  for each pred   [BS, M]
//   [1*32768 .. )  min over preds for each gt    [BS, N]
//   [2*32768 .. )  argmin over gts  (as float)   [BS, M]
//   [3*32768 .. )  argmin over preds (as float)  [BS, N]
//
// Bit-exact numpy fp32 emulation (PASS rounds 6-8), NO FMA anywhere
// (pragma contract(off) — ROCm's __f*_rn do NOT block contraction):
//   rr = ((x*x + y*y) + z*z)           ascending
//   zz = ((x0*y0 + x1*y1) + x2*y2)     ascending, no FMA
//   P  = ((rr_n + rr_m) - (2*zz))      left-to-right; *2 exact
// Packed f32x2 ops = same IEEE-rn rounding => bit-exactness preserved.
//
// Round 9: QT=8 queries/thread (amortize per-row overhead: ds_read, idx,
// loop control over 8 pairs instead of 4); 1 block/CU, 4 waves/SIMD,
// launch_bounds(1024,4) -> VGPR cap 128, no spill risk. One-shot parallel
// merge (4 thr/query + shfl_xor) replacing serial per-j scans; merge LDS
// aliases the candidate buffer (total 48KB).

#define BS     4
#define NPTS   8192
#define CHUNK  1024
#define BLOCK  1024
#define SPLITS 32
#define SLOTS  32                 // query slots per block
#define QT     8                  // queries per thread
#define QBLK   (SLOTS * QT)       // 256 queries per block
#define ROWS   (CHUNK / SPLITS)   // 32 candidate rows per chunk per split

typedef float f32x2 __attribute__((ext_vector_type(2)));

__global__ __launch_bounds__(BLOCK, 4)
void chamfer_kernel(const float* __restrict__ preds,
                    const float* __restrict__ gts,
                    float* __restrict__ out)
{
#pragma clang fp contract(off)
    const int dir   = blockIdx.z;  // 0: per-pred min over gts, 1: per-gt min over preds
    const int b     = blockIdx.y;
    const int t     = threadIdx.x;
    const int slot  = t & (SLOTS - 1);   // query slot within block
    const int split = t >> 5;            // candidate split
    const int qb    = blockIdx.x * QBLK;

    const float* qbase = (dir == 0 ? preds : gts) + (size_t)b * NPTS * 3;
    const float* rbase = (dir == 0 ? gts : preds) + (size_t)b * NPTS * 3;
    float* outv = out + (size_t)dir       * BS * NPTS + (size_t)b * NPTS;
    float* outi = out + (size_t)(2 + dir) * BS * NPTS + (size_t)b * NPTS;

    // 48KB shared: [0,16K) candidate tiles during main loop;
    // after final barrier reused as merge scratch [0,32K) floats + [32K,48K) u16
    __shared__ float smem[12288];
    float (*sh)[4]        = (float (*)[4])smem;                  // [CHUNK][4]
    float *shv            = smem;                                // [SPLITS][QBLK]
    unsigned short *shi16 = (unsigned short *)(smem + 8192);     // [SPLITS][QBLK]

    // QT=8 query points as 4 packed groups (j = 2g+h)
    f32x2 qxv[4], qyv[4], qzv[4], rqv[4];
#pragma unroll
    for (int g = 0; g < 4; ++g) {
#pragma unroll
        for (int h = 0; h < 2; ++h) {
            const int j = g * 2 + h;
            const int q = qb + j * SLOTS + slot;
            const float x = qbase[(size_t)q * 3 + 0];
            const float y = qbase[(size_t)q * 3 + 1];
            const float z = qbase[(size_t)q * 3 + 2];
            qxv[g][h] = x; qyv[g][h] = y; qzv[g][h] = z;
            const float a0 = x * x;
            const float a1 = y * y;
            const float a2 = z * z;
            rqv[g][h] = (a0 + a1) + a2;     // ascending, no FMA
        }
    }

    float bestv[QT];
    int   besti[QT];
#pragma unroll
    for (int j = 0; j < QT; ++j) { bestv[j] = 3.0e38f; besti[j] = 0; }

    const int nchunks = NPTS / CHUNK;
    for (int c = 0; c < nchunks; ++c) {
        __syncthreads();
        {   // stage: each of 1024 threads loads one point
            const size_t n = (size_t)c * CHUNK + t;
            const float x = rbase[n * 3 + 0];
            const float y = rbase[n * 3 + 1];
            const float z = rbase[n * 3 + 2];
            sh[t][0] = x;
            sh[t][1] = y;
            sh[t][2] = z;
            const float a0 = x * x;
            const float a1 = y * y;
            const float a2 = z * z;
            sh[t][3] = (a0 + a1) + a2;     // ascending, no FMA
        }
        __syncthreads();

        const int row0 = split * ROWS;
#pragma unroll 4
        for (int k = 0; k < ROWS; ++k) {
            const int row = row0 + k;
            const float x  = sh[row][0];
            const float y  = sh[row][1];
            const float z  = sh[row][2];
            const float rr = sh[row][3];
            const int idx = c * CHUNK + row;
#pragma unroll
            for (int g = 0; g < 4; ++g) {
                // zz ascending ((d0 + d1) + d2), packed IEEE-rn, no FMA
                const f32x2 p0 = qxv[g] * x;
                const f32x2 p1 = qyv[g] * y;
                const f32x2 p2 = qzv[g] * z;
                const f32x2 zz = (p0 + p1) + p2;
                const f32x2 ts = rqv[g] + rr;    // == rr + rq (commutative)
                const f32x2 w  = zz * 2.0f;
                const f32x2 v  = ts - w;
                if (v[0] < bestv[2 * g + 0]) { bestv[2 * g + 0] = v[0]; besti[2 * g + 0] = idx; }
                if (v[1] < bestv[2 * g + 1]) { bestv[2 * g + 1] = v[1]; besti[2 * g + 1] = idx; }
            }
        }
    }

    // ---- Merge over splits; lex (v, idx) min == numpy first-occurrence argmin
    // (valid: v is bit-identical regardless of which split computes it)
    __syncthreads();   // all reads of sh[] done; safe to overwrite
#pragma unroll
    for (int j = 0; j < QT; ++j) {
        shv  [split * QBLK + j * SLOTS + slot] = bestv[j];
        shi16[split * QBLK + j * SLOTS + slot] = (unsigned short)besti[j];
    }
    __syncthreads();

    // 4 threads per query: each lex-merges 8 splits, then shfl_xor reduce
    const int qloc = t >> 2;       // 0..255
    const int sl   = t & 3;
    float bv = 3.0e38f;
    int   bi = 0;
#pragma unroll
    for (int k = 0; k < SPLITS / 4; ++k) {
        const int s = sl + k * 4;
        const float v2 = shv[s * QBLK + qloc];
        const int   i2 = shi16[s * QBLK + qloc];
        if (v2 < bv || (v2 == bv && i2 < bi)) { bv = v2; bi = i2; }
    }
#pragma unroll
    for (int o = 1; o < 4; o <<= 1) {
        const float ov = __shfl_xor(bv, o);
        const int   oi = __shfl_xor(bi, o);
        if (ov < bv || (ov == bv && oi < bi)) { bv = ov; bi = oi; }
    }
    if (sl == 0) {
        outv[qb + qloc] = bv;
        outi[qb + qloc] = (float)bi;
    }
}

extern "C" void kernel_launch(void* const* d_in, const int* in_sizes, int n_in,
                              void* d_out, int out_size, void* d_ws, size_t ws_size,
                              hipStream_t stream)
{
    const float* preds = (const float*)d_in[0];  // [BS, M, 3]
    const float* gts   = (const float*)d_in[1];  // [BS, N, 3]
    // d_in[2] = mask, unused (matches reference)
    float* out = (float*)d_out;

    dim3 grid(NPTS / QBLK, BS, 2);   // 32 x 4 x 2 = 256 blocks of 1024
    dim3 block(BLOCK);
    chamfer_kernel<<<grid, block, 0, stream>>>(preds, gts, out);
}